// Round 11
// baseline (8966.992 us; speedup 1.0000x reference)
//
#include <hip/hip_runtime.h>
#include <hip/hip_cooperative_groups.h>

namespace cg = cooperative_groups;

#define BB 16
#define TT 2048
#define HIDN 896
#define HALFN 448
#define NBINS 256
#define NWG 112
#define NTHR 64
#define WSTR 904            /* sW padded ushort stride */

typedef __attribute__((ext_vector_type(8))) short short8;
typedef __attribute__((ext_vector_type(4))) float f32x4;
typedef __attribute__((ext_vector_type(2))) unsigned long long ull2;

__device__ __forceinline__ unsigned short f2bf(float x) {
    unsigned int u = __float_as_uint(x);
    unsigned int r = u + 0x7FFFu + ((u >> 16) & 1u);
    return (unsigned short)(r >> 16);
}

// ---------------------------------------------------------------------------
// Persistent GRU scan. 112 WGs x 1 wave (64 thr). WG wg owns col-block
// cb = (wg&7)*14 + (wg>>3) (XCD remap), i.e. h-cols [8cb, 8cb+8).
// r10 structure (fragment-direct hx loads, register x-prefetch) with a
// SINGLE-COUNTER barrier: producers atomic-add ctr[(t+1)&1] after their
// h-store drain; consumers poll one broadcast line until
// ctr[t&1] >= 112*ceil(t/2) (monotonic, no reset, <=1-step skew; publish
// certifies the producer's h(t) loads completed, so parity reuse is safe).
// LDS exactly 57,856 B (proven coop-launch envelope for 64-thr blocks).
// ---------------------------------------------------------------------------
__global__ __launch_bounds__(NTHR, 1)
void scan_kernel(const float* __restrict__ cond,
                 const int*   __restrict__ sig,
                 const int*   __restrict__ tcrs,
                 const float* __restrict__ Wc,
                 const float* __restrict__ Wf,
                 const float* __restrict__ Whh,
                 const float* __restrict__ b_ih,
                 const float* __restrict__ b_hh,
                 unsigned long long* __restrict__ hx,   // [2][112][32] u64 (by cb)
                 unsigned* __restrict__ ctr,            // ctr[0] @ +0, ctr[1] @ +64B
                 unsigned short* __restrict__ hc_out,
                 float* __restrict__ lasth)
{
    __shared__ unsigned short sW[32 * WSTR];   // 57,856 B (only LDS)

    const int tid  = threadIdx.x;
    const int wg   = blockIdx.x;
    const int cb   = (wg & 7) * 14 + (wg >> 3);   // XCD-contiguous col-block
    const int col0 = cb * 8;

    // ---- one-time: W slices -> LDS bf16 ----
    for (int idx = tid; idx < 32 * HIDN; idx += NTHR) {
        int j2 = idx & 31, k = idx >> 5;
        unsigned short wv = 0;
        if (j2 < 16)
            wv = f2bf(Whh[(size_t)k * 2688 + (j2 >> 3) * HIDN + col0 + (j2 & 7)]);
        else if (j2 < 24)
            wv = f2bf(Whh[(size_t)k * 2688 + 2 * HIDN + col0 + (j2 & 7)]);
        sW[j2 * WSTR + k] = wv;
    }
    if (wg == 0 && tid == 0) {      // replay-safe counter reset
        __hip_atomic_store(&ctr[0],  0u, __ATOMIC_RELAXED, __HIP_MEMORY_SCOPE_AGENT);
        __hip_atomic_store(&ctr[16], 0u, __ATOMIC_RELAXED, __HIP_MEMORY_SCOPE_AGENT);
    }

    // ---- lane roles ----
    const int l  = tid;
    const int q  = l & 15;
    const int hi = l >> 4;
    const int gA   = q >> 3;            // 0 = r-gate, 1 = z-gate (tile A)
    const int colA = col0 + (q & 7);

    float wpA0, wpA1, wpA2, wpB0, wpB1, wpB2;
    if (colA < HALFN) {
        wpA0 = Wc[gA * HALFN + colA];
        wpA1 = Wc[1344 + gA * HALFN + colA];
        wpA2 = 0.f;
        wpB0 = Wc[2 * HALFN + colA];
        wpB1 = Wc[1344 + 2 * HALFN + colA];
        wpB2 = 0.f;
    } else {
        int ck = colA - HALFN;
        wpA0 = Wf[gA * HALFN + ck];
        wpA1 = Wf[1344 + gA * HALFN + ck];
        wpA2 = Wf[2688 + gA * HALFN + ck];
        wpB0 = Wf[2 * HALFN + ck];
        wpB1 = Wf[1344 + 2 * HALFN + ck];
        wpB2 = Wf[2688 + 2 * HALFN + ck];
    }
    const float biA = b_ih[gA * HIDN + colA];
    const float bhA = b_hh[gA * HIDN + colA];
    const float biB = b_ih[2 * HIDN + colA];
    const float bhB = b_hh[2 * HIDN + colA];

    float hp[4] = {0.f, 0.f, 0.f, 0.f};

    // ---- x prefetch registers (single set; overwritten post-publish) ----
    float xcA[4], xcB[4];
    int   si0[4], si1[4], si2[4];

#define PREFETCH(tt) {                                                         \
    int tn_ = (tt) < TT ? (tt) : TT - 1;                                       \
    _Pragma("unroll")                                                          \
    for (int r_ = 0; r_ < 4; ++r_) {                                           \
        size_t bt_ = (size_t)(hi * 4 + r_) * TT + tn_;                         \
        xcA[r_] = cond[(bt_ * 3 + gA) * HIDN + colA];                          \
        xcB[r_] = cond[(bt_ * 3 + 2) * HIDN + colA];                           \
        si0[r_] = sig[bt_ * 2 + 0];                                            \
        si1[r_] = sig[bt_ * 2 + 1];                                            \
        si2[r_] = tcrs[bt_];                                                   \
    } }

    PREFETCH(0);                      // x for t=0 (completes during prologue)

    __syncthreads();                 // sW visible wave-wide
    cg::this_grid().sync();          // counter reset visible grid-wide

    const float inv = 1.f / 127.5f;
    const int zsrc = (l & 48) | 8 | (q & 7);   // z-lane, same hi

    // ---- single-counter wait: all 112 producers published h(t) ----
#define WAITCTR(t) {                                                           \
    const unsigned tgt_ = 112u * (unsigned)(((t) + 1) >> 1);                   \
    for (;;) {                                                                 \
        unsigned c_ = __hip_atomic_load(&ctr[((t) & 1) * 16],                  \
            __ATOMIC_RELAXED, __HIP_MEMORY_SCOPE_AGENT);                       \
        if (c_ >= tgt_) break;                                                 \
        __builtin_amdgcn_s_sleep(1);                                           \
    }                                                                          \
    asm volatile("" ::: "memory"); }

    // Lane (q,hi): A-frag for K-step ks = cols of col-block 4ks+hi, batch q.
#define LOADH(s, V) _Pragma("unroll")                                          \
    for (int i_ = 0; i_ < 7; ++i_) {                                           \
        _Pragma("unroll")                                                      \
        for (int h_ = 0; h_ < 2; ++h_)                                         \
            V[2*i_ + h_] = __hip_atomic_load(                                  \
                &hb[(size_t)(4 * ((s)*7 + i_) + hi) * 32 + h_ * 16 + q],       \
                __ATOMIC_RELAXED, __HIP_MEMORY_SCOPE_AGENT);                   \
    }

#define MFMAS(s, V) _Pragma("unroll")                                          \
    for (int i_ = 0; i_ < 7; ++i_) {                                           \
        ull2 tv_; tv_.x = V[2*i_]; tv_.y = V[2*i_ + 1];                        \
        short8 av_ = __builtin_bit_cast(short8, tv_);                          \
        int ks_ = (s)*7 + i_;                                                  \
        short8 b1_ = *(const short8*)&sW[q * WSTR + hi * 8 + ks_ * 32];        \
        chA[ks_ & 3] = __builtin_amdgcn_mfma_f32_16x16x32_bf16(                \
            av_, b1_, chA[ks_ & 3], 0, 0, 0);                                  \
        short8 b2_ = *(const short8*)&sW[(16 + q) * WSTR + hi * 8 + ks_ * 32]; \
        chB[ks_ & 3] = __builtin_amdgcn_mfma_f32_16x16x32_bf16(                \
            av_, b2_, chB[ks_ & 3], 0, 0, 0);                                  \
    }

    for (int t = 0; t < TT; ++t) {
        f32x4 chA[4] = {}, chB[4] = {};
        if (t > 0) {
            WAITCTR(t);
            const unsigned long long* hb = hx + (size_t)(t & 1) * 3584;
            unsigned long long va[14], vb[14];
            LOADH(0, va);
            LOADH(1, vb);
            MFMAS(0, va);
            LOADH(2, va);
            MFMAS(1, vb);
            LOADH(3, vb);
            MFMAS(2, va);
            MFMAS(3, vb);
        }
        f32x4 aA = (chA[0] + chA[1]) + (chA[2] + chA[3]);
        f32x4 aB = (chB[0] + chB[1]) + (chB[2] + chB[3]);

        // ---- gates (x from prefetched regs -- no fresh HBM deps) ----
        float xvB[4], sigA[4];
        #pragma unroll
        for (int r = 0; r < 4; ++r) {
            float g0 = (float)si0[r] * inv - 1.f;
            float g1 = (float)si1[r] * inv - 1.f;
            float g2 = (float)si2[r] * inv - 1.f;
            float xvA = xcA[r] + biA + g0*wpA0 + g1*wpA1 + g2*wpA2;
            xvB[r]    = xcB[r] + biB + g0*wpB0 + g1*wpB1 + g2*wpB2;
            sigA[r] = 1.f / (1.f + __expf(-(xvA + aA[r] + bhA)));
        }
        float hnv[4];
        unsigned short hbits[4] = {0, 0, 0, 0};
        #pragma unroll
        for (int r = 0; r < 4; ++r) {
            float zz = __shfl(sigA[r], zsrc);          // z from q+8 lane
            float a2v = xvB[r] + sigA[r] * (aB[r] + bhB);  // r on q<8 lanes
            float e = __expf(-2.f * a2v);
            float n = (1.f - e) / (1.f + e);
            float hn = (1.f - zz) * n + zz * hp[r];
            hnv[r] = hn;
            if (q < 8) { hp[r] = hn; hbits[r] = f2bf(hn); }
        }
        if (t == TT - 1 && q < 8) {
            #pragma unroll
            for (int r = 0; r < 4; ++r)
                lasth[(size_t)(hi * 4 + r) * HIDN + colA] = hnv[r];
        }

        // ---- pack 8 cols -> 2 u64 per batch; store; drain; publish ----
        unsigned p32[4];
        unsigned long long hv64[4];
        #pragma unroll
        for (int r = 0; r < 4; ++r) {
            int o1 = __shfl_xor((int)(unsigned)hbits[r], 1);
            p32[r] = ((unsigned)hbits[r] & 0xffffu) | ((unsigned)o1 << 16);
            int o2 = __shfl_xor((int)p32[r], 2);
            hv64[r] = (unsigned long long)p32[r] |
                      ((unsigned long long)(unsigned)o2 << 32);
        }
        if (t < TT - 1 && (q == 0 || q == 4)) {
            unsigned long long* hd = hx + (size_t)((t + 1) & 1) * 3584;
            #pragma unroll
            for (int r = 0; r < 4; ++r)
                __hip_atomic_store(&hd[(size_t)cb * 32 + (q >> 2) * 16 + hi * 4 + r],
                                   hv64[r], __ATOMIC_RELAXED, __HIP_MEMORY_SCOPE_AGENT);
        }
        asm volatile("s_waitcnt vmcnt(0)" ::: "memory");
        if (tid == 0)
            __hip_atomic_fetch_add(&ctr[((t + 1) & 1) * 16], 1u,
                                   __ATOMIC_RELAXED, __HIP_MEMORY_SCOPE_AGENT);

        // ---- post-publish: prefetch next x, then history write ----
        PREFETCH(t + 1);
        if (cb < 56 && q < 8 && !(q & 1)) {
            unsigned* hc32 = (unsigned*)hc_out;
            #pragma unroll
            for (int r = 0; r < 4; ++r)
                hc32[((size_t)(hi * 4 + r) * TT + t) * 224 + cb * 4 + (q >> 1)] = p32[r];
        }
    }
#undef WAITCTR
#undef LOADH
#undef MFMAS
#undef PREFETCH
}

// ---------------------------------------------------------------------------
// Head GEMM (MFMA bf16): C(M x N) = [relu](A_bf16(M x 448) @ Bw_f32(448 x N)
// + bias). 128x64 tile, 256 thr = 4 waves (2x2), fp32 accum.
// Fragment convention identical to scan_kernel (verified passing r5-r10):
// A-frag lane l: row=l&15, k=(l>>4)*8+0..7 (k-contiguous LDS);
// B-frag lane l: col=l&15, k=(l>>4)*8+0..7 (B transposed in LDS);
// D: col=l&15, row=(l>>4)*4+reg.
// ---------------------------------------------------------------------------
template<int RELU_BF16>
__global__ __launch_bounds__(256)
void head_gemm(const unsigned short* __restrict__ A,
               const float* __restrict__ Bw,
               const float* __restrict__ bias,
               unsigned short* __restrict__ Cb,
               float* __restrict__ Cf,
               int N)
{
    const int K = 448;
    __shared__ unsigned short sA[128 * 40];    // 10,240 B
    __shared__ unsigned short sBt[64 * 40];    //  5,120 B (transposed: [col][k])
    const int tid = threadIdx.x;
    const int w   = tid >> 6;
    const int l   = tid & 63;
    const int wm  = (w >> 1) * 64;     // wave row offset
    const int wn  = (w & 1) * 32;      // wave col offset
    const int bm  = blockIdx.x * 128;
    const int bn  = blockIdx.y * 64;

    f32x4 acc[4][2] = {};

    for (int k0 = 0; k0 < K; k0 += 32) {
        // stage A: 128 rows x 32 k (bf16, 16B chunks)
        #pragma unroll
        for (int it = 0; it < 2; ++it) {
            int idx = tid + it * 256;       // 0..511
            int row = idx >> 2;
            int ck  = (idx & 3) * 8;
            *(float4*)&sA[row * 40 + ck] =
                *(const float4*)(A + (size_t)(bm + row) * K + k0 + ck);
        }
        // stage B transposed: read coalesced f32, write bf16 [col][k]
        #pragma unroll
        for (int it = 0; it < 2; ++it) {
            int idx = tid + it * 256;       // 0..511
            int kk = idx >> 4;              // 0..31
            int c4 = (idx & 15) * 4;        // 0..60
            float4 v = *(const float4*)(Bw + (size_t)(k0 + kk) * N + bn + c4);
            sBt[(c4 + 0) * 40 + kk] = f2bf(v.x);
            sBt[(c4 + 1) * 40 + kk] = f2bf(v.y);
            sBt[(c4 + 2) * 40 + kk] = f2bf(v.z);
            sBt[(c4 + 3) * 40 + kk] = f2bf(v.w);
        }
        __syncthreads();
        const int kq = (l >> 4) * 8;
        short8 bv0 = *(const short8*)&sBt[(wn + (l & 15)) * 40 + kq];
        short8 bv1 = *(const short8*)&sBt[(wn + 16 + (l & 15)) * 40 + kq];
        #pragma unroll
        for (int rb = 0; rb < 4; ++rb) {
            short8 av = *(const short8*)&sA[(wm + rb * 16 + (l & 15)) * 40 + kq];
            acc[rb][0] = __builtin_amdgcn_mfma_f32_16x16x32_bf16(av, bv0, acc[rb][0], 0, 0, 0);
            acc[rb][1] = __builtin_amdgcn_mfma_f32_16x16x32_bf16(av, bv1, acc[rb][1], 0, 0, 0);
        }
        __syncthreads();
    }

    #pragma unroll
    for (int rb = 0; rb < 4; ++rb) {
        #pragma unroll
        for (int cbk = 0; cbk < 2; ++cbk) {
            int col = bn + wn + cbk * 16 + (l & 15);
            float bv = bias[col];
            #pragma unroll
            for (int j = 0; j < 4; ++j) {
                int row = bm + wm + rb * 16 + (l >> 4) * 4 + j;
                float v = acc[rb][cbk][j] + bv;
                if (RELU_BF16)
                    Cb[(size_t)row * N + col] = f2bf(fmaxf(v, 0.f));
                else
                    Cf[(size_t)row * N + col] = v;
            }
        }
    }
}

// ---------------------------------------------------------------------------
extern "C" void kernel_launch(void* const* d_in, const int* in_sizes, int n_in,
                              void* d_out, int out_size, void* d_ws, size_t ws_size,
                              hipStream_t stream)
{
    const float* cond = (const float*)d_in[0];
    const int*   sig  = (const int*)d_in[1];
    const int*   tcrs = (const int*)d_in[2];
    const float* Wc   = (const float*)d_in[3];
    const float* Wf   = (const float*)d_in[4];
    const float* Whh  = (const float*)d_in[5];
    const float* bih  = (const float*)d_in[6];
    const float* bhh  = (const float*)d_in[7];
    const float* W1c  = (const float*)d_in[8];
    const float* b1c  = (const float*)d_in[9];
    const float* W2c  = (const float*)d_in[10];
    const float* b2c  = (const float*)d_in[11];
    const float* W1f  = (const float*)d_in[12];
    const float* b1f  = (const float*)d_in[13];
    const float* W2f  = (const float*)d_in[14];
    const float* b2f  = (const float*)d_in[15];

    char* ws = (char*)d_ws;
    unsigned* ctr            = (unsigned*)ws;                    // 128 B used
    unsigned long long* hx   = (unsigned long long*)(ws + 8192); // 57,344 B
    unsigned short* hc       = (unsigned short*)(ws + 65536);    // 29,360,128 B
    unsigned short* hid1     = (unsigned short*)(ws + 65536 + 29360128);

    float* outc  = (float*)d_out;
    float* outf  = outc + (size_t)BB * TT * NBINS;
    float* lasth = outc + 2 * (size_t)BB * TT * NBINS;

    void* args[] = {(void*)&cond, (void*)&sig, (void*)&tcrs, (void*)&Wc, (void*)&Wf,
                    (void*)&Whh, (void*)&bih, (void*)&bhh,
                    (void*)&hx, (void*)&ctr, (void*)&hc, (void*)&lasth};
    hipLaunchCooperativeKernel((void*)scan_kernel, dim3(NWG), dim3(NTHR),
                               args, 0, stream);

    dim3 blk(256);
    head_gemm<1><<<dim3(256, 7), blk, 0, stream>>>(hc,   W1c, b1c, hid1, nullptr, 448);
    head_gemm<0><<<dim3(256, 4), blk, 0, stream>>>(hid1, W2c, b2c, nullptr, outc, 256);
    head_gemm<1><<<dim3(256, 7), blk, 0, stream>>>(hc,   W1f, b1f, hid1, nullptr, 448);
    head_gemm<0><<<dim3(256, 4), blk, 0, stream>>>(hid1, W2f, b2f, nullptr, outf, 256);
}

// Round 12
// 7708.110 us; speedup vs baseline: 1.1633x; 1.1633x over previous
//
#include <hip/hip_runtime.h>
#include <hip/hip_cooperative_groups.h>

namespace cg = cooperative_groups;

#define BB 16
#define TT 2048
#define HIDN 896
#define HALFN 448
#define NBINS 256
#define NWG 112
#define NTHR 64
#define WSTR 904            /* sW padded ushort stride */

typedef __attribute__((ext_vector_type(8))) short short8;
typedef __attribute__((ext_vector_type(4))) float f32x4;
typedef __attribute__((ext_vector_type(2))) unsigned long long ull2;

__device__ __forceinline__ unsigned short f2bf(float x) {
    unsigned int u = __float_as_uint(x);
    unsigned int r = u + 0x7FFFu + ((u >> 16) & 1u);
    return (unsigned short)(r >> 16);
}

// ---------------------------------------------------------------------------
// Persistent GRU scan (r10 verbatim -- best measured: 7.58 ms).
// 112 WGs x 1 wave. WG wg owns col-block cb = (wg&7)*14 + (wg>>3) (XCD
// remap), h-cols [8cb, 8cb+8). Slot barrier (112 padded lines, parallel
// stores + parallel sweep), fragment-direct hx loads (no LDS staging),
// register x-prefetch issued post-publish. LDS exactly 57,856 B.
// Floor analysis: 3 serialized agent-scope RTs/step (drain, detect, load)
// ~= 3.3 us + 0.4 us compute = 3.7 us/step. All protocol variants tried
// (tag-in-value, K-sliced waits, single counter) matched or regressed.
// ---------------------------------------------------------------------------
__global__ __launch_bounds__(NTHR, 1)
void scan_kernel(const float* __restrict__ cond,
                 const int*   __restrict__ sig,
                 const int*   __restrict__ tcrs,
                 const float* __restrict__ Wc,
                 const float* __restrict__ Wf,
                 const float* __restrict__ Whh,
                 const float* __restrict__ b_ih,
                 const float* __restrict__ b_hh,
                 unsigned long long* __restrict__ hx,   // [2][112][32] u64 (by cb)
                 int* __restrict__ slots,               // [112*16] padded
                 unsigned short* __restrict__ hc_out,
                 float* __restrict__ lasth)
{
    __shared__ unsigned short sW[32 * WSTR];   // 57,856 B (only LDS)

    const int tid  = threadIdx.x;
    const int wg   = blockIdx.x;
    const int cb   = (wg & 7) * 14 + (wg >> 3);   // XCD-contiguous col-block
    const int col0 = cb * 8;

    // ---- one-time: W slices -> LDS bf16 ----
    for (int idx = tid; idx < 32 * HIDN; idx += NTHR) {
        int j2 = idx & 31, k = idx >> 5;
        unsigned short wv = 0;
        if (j2 < 16)
            wv = f2bf(Whh[(size_t)k * 2688 + (j2 >> 3) * HIDN + col0 + (j2 & 7)]);
        else if (j2 < 24)
            wv = f2bf(Whh[(size_t)k * 2688 + 2 * HIDN + col0 + (j2 & 7)]);
        sW[j2 * WSTR + k] = wv;
    }
    if (tid == 0)
        __hip_atomic_store(&slots[wg * 16], 0, __ATOMIC_RELAXED, __HIP_MEMORY_SCOPE_AGENT);

    // ---- lane roles ----
    const int l  = tid;
    const int q  = l & 15;
    const int hi = l >> 4;
    const int gA   = q >> 3;            // 0 = r-gate, 1 = z-gate (tile A)
    const int colA = col0 + (q & 7);

    float wpA0, wpA1, wpA2, wpB0, wpB1, wpB2;
    if (colA < HALFN) {
        wpA0 = Wc[gA * HALFN + colA];
        wpA1 = Wc[1344 + gA * HALFN + colA];
        wpA2 = 0.f;
        wpB0 = Wc[2 * HALFN + colA];
        wpB1 = Wc[1344 + 2 * HALFN + colA];
        wpB2 = 0.f;
    } else {
        int ck = colA - HALFN;
        wpA0 = Wf[gA * HALFN + ck];
        wpA1 = Wf[1344 + gA * HALFN + ck];
        wpA2 = Wf[2688 + gA * HALFN + ck];
        wpB0 = Wf[2 * HALFN + ck];
        wpB1 = Wf[1344 + 2 * HALFN + ck];
        wpB2 = Wf[2688 + 2 * HALFN + ck];
    }
    const float biA = b_ih[gA * HIDN + colA];
    const float bhA = b_hh[gA * HIDN + colA];
    const float biB = b_ih[2 * HIDN + colA];
    const float bhB = b_hh[2 * HIDN + colA];

    float hp[4] = {0.f, 0.f, 0.f, 0.f};

    // ---- x prefetch registers (single set; overwritten post-publish) ----
    float xcA[4], xcB[4];
    int   si0[4], si1[4], si2[4];

#define PREFETCH(tt) {                                                         \
    int tn_ = (tt) < TT ? (tt) : TT - 1;                                       \
    _Pragma("unroll")                                                          \
    for (int r_ = 0; r_ < 4; ++r_) {                                           \
        size_t bt_ = (size_t)(hi * 4 + r_) * TT + tn_;                         \
        xcA[r_] = cond[(bt_ * 3 + gA) * HIDN + colA];                          \
        xcB[r_] = cond[(bt_ * 3 + 2) * HIDN + colA];                           \
        si0[r_] = sig[bt_ * 2 + 0];                                            \
        si1[r_] = sig[bt_ * 2 + 1];                                            \
        si2[r_] = tcrs[bt_];                                                   \
    } }

    PREFETCH(0);                      // x for t=0 (completes during prologue)

    __syncthreads();                 // sW visible wave-wide
    cg::this_grid().sync();          // slot clears visible grid-wide

    const float inv = 1.f / 127.5f;
    const int zsrc = (l & 48) | 8 | (q & 7);   // z-lane, same hi

    // ---- single wait on all 112 producer slots (parallel sweep) ----
#define WAITALL(t) { bool ok_;                                                 \
    for (;;) {                                                                 \
        int a_ = __hip_atomic_load(&slots[l * 16],                             \
            __ATOMIC_RELAXED, __HIP_MEMORY_SCOPE_AGENT);                       \
        int b_ = (l < 48) ? __hip_atomic_load(&slots[(l + 64) * 16],           \
            __ATOMIC_RELAXED, __HIP_MEMORY_SCOPE_AGENT) : a_;                  \
        ok_ = (a_ >= (t)) & (b_ >= (t));                                       \
        if (__all(ok_)) break;                                                 \
        __builtin_amdgcn_s_sleep(1);                                           \
    }                                                                          \
    asm volatile("" ::: "memory"); }

    // Lane (q,hi): A-frag for K-step ks = cols of col-block 4ks+hi, batch q.
#define LOADH(s, V) _Pragma("unroll")                                          \
    for (int i_ = 0; i_ < 7; ++i_) {                                           \
        _Pragma("unroll")                                                      \
        for (int h_ = 0; h_ < 2; ++h_)                                         \
            V[2*i_ + h_] = __hip_atomic_load(                                  \
                &hb[(size_t)(4 * ((s)*7 + i_) + hi) * 32 + h_ * 16 + q],       \
                __ATOMIC_RELAXED, __HIP_MEMORY_SCOPE_AGENT);                   \
    }

#define MFMAS(s, V) _Pragma("unroll")                                          \
    for (int i_ = 0; i_ < 7; ++i_) {                                           \
        ull2 tv_; tv_.x = V[2*i_]; tv_.y = V[2*i_ + 1];                        \
        short8 av_ = __builtin_bit_cast(short8, tv_);                          \
        int ks_ = (s)*7 + i_;                                                  \
        short8 b1_ = *(const short8*)&sW[q * WSTR + hi * 8 + ks_ * 32];        \
        chA[ks_ & 3] = __builtin_amdgcn_mfma_f32_16x16x32_bf16(                \
            av_, b1_, chA[ks_ & 3], 0, 0, 0);                                  \
        short8 b2_ = *(const short8*)&sW[(16 + q) * WSTR + hi * 8 + ks_ * 32]; \
        chB[ks_ & 3] = __builtin_amdgcn_mfma_f32_16x16x32_bf16(                \
            av_, b2_, chB[ks_ & 3], 0, 0, 0);                                  \
    }

    for (int t = 0; t < TT; ++t) {
        f32x4 chA[4] = {}, chB[4] = {};
        if (t > 0) {
            WAITALL(t);
            const unsigned long long* hb = hx + (size_t)(t & 1) * 3584;
            unsigned long long va[14], vb[14];
            LOADH(0, va);
            LOADH(1, vb);
            MFMAS(0, va);
            LOADH(2, va);
            MFMAS(1, vb);
            LOADH(3, vb);
            MFMAS(2, va);
            MFMAS(3, vb);
        }
        f32x4 aA = (chA[0] + chA[1]) + (chA[2] + chA[3]);
        f32x4 aB = (chB[0] + chB[1]) + (chB[2] + chB[3]);

        // ---- gates (x from prefetched regs -- no fresh HBM deps) ----
        float xvB[4], sigA[4];
        #pragma unroll
        for (int r = 0; r < 4; ++r) {
            float g0 = (float)si0[r] * inv - 1.f;
            float g1 = (float)si1[r] * inv - 1.f;
            float g2 = (float)si2[r] * inv - 1.f;
            float xvA = xcA[r] + biA + g0*wpA0 + g1*wpA1 + g2*wpA2;
            xvB[r]    = xcB[r] + biB + g0*wpB0 + g1*wpB1 + g2*wpB2;
            sigA[r] = 1.f / (1.f + __expf(-(xvA + aA[r] + bhA)));
        }
        float hnv[4];
        unsigned short hbits[4] = {0, 0, 0, 0};
        #pragma unroll
        for (int r = 0; r < 4; ++r) {
            float zz = __shfl(sigA[r], zsrc);          // z from q+8 lane
            float a2v = xvB[r] + sigA[r] * (aB[r] + bhB);  // r on q<8 lanes
            float e = __expf(-2.f * a2v);
            float n = (1.f - e) / (1.f + e);
            float hn = (1.f - zz) * n + zz * hp[r];
            hnv[r] = hn;
            if (q < 8) { hp[r] = hn; hbits[r] = f2bf(hn); }
        }
        if (t == TT - 1 && q < 8) {
            #pragma unroll
            for (int r = 0; r < 4; ++r)
                lasth[(size_t)(hi * 4 + r) * HIDN + colA] = hnv[r];
        }

        // ---- pack 8 cols -> 2 u64 per batch; store; drain; publish ----
        unsigned p32[4];
        unsigned long long hv64[4];
        #pragma unroll
        for (int r = 0; r < 4; ++r) {
            int o1 = __shfl_xor((int)(unsigned)hbits[r], 1);
            p32[r] = ((unsigned)hbits[r] & 0xffffu) | ((unsigned)o1 << 16);
            int o2 = __shfl_xor((int)p32[r], 2);
            hv64[r] = (unsigned long long)p32[r] |
                      ((unsigned long long)(unsigned)o2 << 32);
        }
        if (t < TT - 1 && (q == 0 || q == 4)) {
            unsigned long long* hd = hx + (size_t)((t + 1) & 1) * 3584;
            #pragma unroll
            for (int r = 0; r < 4; ++r)
                __hip_atomic_store(&hd[(size_t)cb * 32 + (q >> 2) * 16 + hi * 4 + r],
                                   hv64[r], __ATOMIC_RELAXED, __HIP_MEMORY_SCOPE_AGENT);
        }
        asm volatile("s_waitcnt vmcnt(0)" ::: "memory");
        if (tid == 0)
            __hip_atomic_store(&slots[wg * 16], t + 1,
                               __ATOMIC_RELAXED, __HIP_MEMORY_SCOPE_AGENT);

        // ---- post-publish: prefetch next x, then history write ----
        PREFETCH(t + 1);
        if (cb < 56 && q < 8 && !(q & 1)) {
            unsigned* hc32 = (unsigned*)hc_out;
            #pragma unroll
            for (int r = 0; r < 4; ++r)
                hc32[((size_t)(hi * 4 + r) * TT + t) * 224 + cb * 4 + (q >> 1)] = p32[r];
        }
    }
#undef WAITALL
#undef LOADH
#undef MFMAS
#undef PREFETCH
}

// ---------------------------------------------------------------------------
// Head GEMM (MFMA bf16, r11 verbatim -- ~130 us total for 4 dispatches):
// C(M x N) = [relu](A_bf16(M x 448) @ Bw_f32(448 x N) + bias).
// 128x64 tile, 256 thr = 4 waves (2x2), fp32 accum.
// ---------------------------------------------------------------------------
template<int RELU_BF16>
__global__ __launch_bounds__(256)
void head_gemm(const unsigned short* __restrict__ A,
               const float* __restrict__ Bw,
               const float* __restrict__ bias,
               unsigned short* __restrict__ Cb,
               float* __restrict__ Cf,
               int N)
{
    const int K = 448;
    __shared__ unsigned short sA[128 * 40];    // 10,240 B
    __shared__ unsigned short sBt[64 * 40];    //  5,120 B (transposed: [col][k])
    const int tid = threadIdx.x;
    const int w   = tid >> 6;
    const int l   = tid & 63;
    const int wm  = (w >> 1) * 64;     // wave row offset
    const int wn  = (w & 1) * 32;      // wave col offset
    const int bm  = blockIdx.x * 128;
    const int bn  = blockIdx.y * 64;

    f32x4 acc[4][2] = {};

    for (int k0 = 0; k0 < K; k0 += 32) {
        #pragma unroll
        for (int it = 0; it < 2; ++it) {
            int idx = tid + it * 256;       // 0..511
            int row = idx >> 2;
            int ck  = (idx & 3) * 8;
            *(float4*)&sA[row * 40 + ck] =
                *(const float4*)(A + (size_t)(bm + row) * K + k0 + ck);
        }
        #pragma unroll
        for (int it = 0; it < 2; ++it) {
            int idx = tid + it * 256;       // 0..511
            int kk = idx >> 4;              // 0..31
            int c4 = (idx & 15) * 4;        // 0..60
            float4 v = *(const float4*)(Bw + (size_t)(k0 + kk) * N + bn + c4);
            sBt[(c4 + 0) * 40 + kk] = f2bf(v.x);
            sBt[(c4 + 1) * 40 + kk] = f2bf(v.y);
            sBt[(c4 + 2) * 40 + kk] = f2bf(v.z);
            sBt[(c4 + 3) * 40 + kk] = f2bf(v.w);
        }
        __syncthreads();
        const int kq = (l >> 4) * 8;
        short8 bv0 = *(const short8*)&sBt[(wn + (l & 15)) * 40 + kq];
        short8 bv1 = *(const short8*)&sBt[(wn + 16 + (l & 15)) * 40 + kq];
        #pragma unroll
        for (int rb = 0; rb < 4; ++rb) {
            short8 av = *(const short8*)&sA[(wm + rb * 16 + (l & 15)) * 40 + kq];
            acc[rb][0] = __builtin_amdgcn_mfma_f32_16x16x32_bf16(av, bv0, acc[rb][0], 0, 0, 0);
            acc[rb][1] = __builtin_amdgcn_mfma_f32_16x16x32_bf16(av, bv1, acc[rb][1], 0, 0, 0);
        }
        __syncthreads();
    }

    #pragma unroll
    for (int rb = 0; rb < 4; ++rb) {
        #pragma unroll
        for (int cbk = 0; cbk < 2; ++cbk) {
            int col = bn + wn + cbk * 16 + (l & 15);
            float bv = bias[col];
            #pragma unroll
            for (int j = 0; j < 4; ++j) {
                int row = bm + wm + rb * 16 + (l >> 4) * 4 + j;
                float v = acc[rb][cbk][j] + bv;
                if (RELU_BF16)
                    Cb[(size_t)row * N + col] = f2bf(fmaxf(v, 0.f));
                else
                    Cf[(size_t)row * N + col] = v;
            }
        }
    }
}

// ---------------------------------------------------------------------------
extern "C" void kernel_launch(void* const* d_in, const int* in_sizes, int n_in,
                              void* d_out, int out_size, void* d_ws, size_t ws_size,
                              hipStream_t stream)
{
    const float* cond = (const float*)d_in[0];
    const int*   sig  = (const int*)d_in[1];
    const int*   tcrs = (const int*)d_in[2];
    const float* Wc   = (const float*)d_in[3];
    const float* Wf   = (const float*)d_in[4];
    const float* Whh  = (const float*)d_in[5];
    const float* bih  = (const float*)d_in[6];
    const float* bhh  = (const float*)d_in[7];
    const float* W1c  = (const float*)d_in[8];
    const float* b1c  = (const float*)d_in[9];
    const float* W2c  = (const float*)d_in[10];
    const float* b2c  = (const float*)d_in[11];
    const float* W1f  = (const float*)d_in[12];
    const float* b1f  = (const float*)d_in[13];
    const float* W2f  = (const float*)d_in[14];
    const float* b2f  = (const float*)d_in[15];

    char* ws = (char*)d_ws;
    int* slots               = (int*)ws;                         // 7,168 B (8K pad)
    unsigned long long* hx   = (unsigned long long*)(ws + 8192); // 57,344 B
    unsigned short* hc       = (unsigned short*)(ws + 65536);    // 29,360,128 B
    unsigned short* hid1     = (unsigned short*)(ws + 65536 + 29360128);

    float* outc  = (float*)d_out;
    float* outf  = outc + (size_t)BB * TT * NBINS;
    float* lasth = outc + 2 * (size_t)BB * TT * NBINS;

    void* args[] = {(void*)&cond, (void*)&sig, (void*)&tcrs, (void*)&Wc, (void*)&Wf,
                    (void*)&Whh, (void*)&bih, (void*)&bhh,
                    (void*)&hx, (void*)&slots, (void*)&hc, (void*)&lasth};
    hipLaunchCooperativeKernel((void*)scan_kernel, dim3(NWG), dim3(NTHR),
                               args, 0, stream);

    dim3 blk(256);
    head_gemm<1><<<dim3(256, 7), blk, 0, stream>>>(hc,   W1c, b1c, hid1, nullptr, 448);
    head_gemm<0><<<dim3(256, 4), blk, 0, stream>>>(hid1, W2c, b2c, nullptr, outc, 256);
    head_gemm<1><<<dim3(256, 7), blk, 0, stream>>>(hc,   W1f, b1f, hid1, nullptr, 448);
    head_gemm<0><<<dim3(256, 4), blk, 0, stream>>>(hid1, W2f, b2f, nullptr, outf, 256);
}

// Round 13
// 7522.182 us; speedup vs baseline: 1.1921x; 1.0247x over previous
//
#include <hip/hip_runtime.h>
#include <hip/hip_cooperative_groups.h>

namespace cg = cooperative_groups;

#define BB 16
#define TT 2048
#define HIDN 896
#define HALFN 448
#define NBINS 256
#define NWG 56
#define NTHR 256
#define WSTR 904            /* sW padded ushort stride */

typedef __attribute__((ext_vector_type(8))) short short8;
typedef __attribute__((ext_vector_type(4))) float f32x4;
typedef __attribute__((ext_vector_type(2))) unsigned long long ull2;

__device__ __forceinline__ unsigned short f2bf(float x) {
    unsigned int u = __float_as_uint(x);
    unsigned int r = u + 0x7FFFu + ((u >> 16) & 1u);
    return (unsigned short)(r >> 16);
}

// ---------------------------------------------------------------------------
// Persistent GRU scan. 56 WGs x 256 thr; only WAVE 0 runs the loop (waves
// 1-3 help the W prologue, grid-sync, exit). WG wg owns col-block
// cb = (wg&7)*7 + (wg>>3) (XCD remap), h-cols [16cb, 16cb+16).
// 16 cols => halved redundancy: consumer broadcast 1.6 MB/step (was 3.2),
// 56 slots (single-load sweep), 56-WG straggler pool.
// Wave-0 lane (q=l&15, hi=l>>4) computes 3 gate tiles (r,z,n) of 16x16:
// same D layout => r/z/n lane-local, no shfl. 84 MFMAs/step.
// h exchange: hx[2][224 chunks][16 batches] u64 (4 bf16 cols per chunk);
// lane's A-frag for K-step ks = chunks {8ks+2hi, +1} at batch q.
// Protocol identical to r10: store -> vmcnt(0) -> slot, WAITALL, loads.
// LDS = 86,784 B (256-thr coop envelope proven to 94,720 B in r4).
// ---------------------------------------------------------------------------
__global__ __launch_bounds__(NTHR, 1)
void scan_kernel(const float* __restrict__ cond,
                 const int*   __restrict__ sig,
                 const int*   __restrict__ tcrs,
                 const float* __restrict__ Wc,
                 const float* __restrict__ Wf,
                 const float* __restrict__ Whh,
                 const float* __restrict__ b_ih,
                 const float* __restrict__ b_hh,
                 unsigned long long* __restrict__ hx,   // [2][224][16] u64
                 int* __restrict__ slots,               // [56*16] padded
                 unsigned short* __restrict__ hc_out,
                 float* __restrict__ lasth)
{
    __shared__ unsigned short sW[48 * WSTR];   // 86,784 B (only LDS)

    const int tid  = threadIdx.x;
    const int wg   = blockIdx.x;
    const int cb   = (wg & 7) * 7 + (wg >> 3);    // XCD-contiguous col-block
    const int col0 = cb * 16;

    // ---- one-time: W slices -> LDS bf16 (all 256 threads) ----
    // row j2 = gate*16 + c  (48 rows, no padding rows), transposed [j2][k].
    for (int idx = tid; idx < 48 * HIDN; idx += NTHR) {
        int j2 = idx % 48, k = idx / 48;
        int g = j2 >> 4, c = j2 & 15;
        sW[j2 * WSTR + k] =
            f2bf(Whh[(size_t)k * 2688 + g * HIDN + col0 + c]);
    }
    if (tid == 0)
        __hip_atomic_store(&slots[wg * 16], 0, __ATOMIC_RELAXED, __HIP_MEMORY_SCOPE_AGENT);

    __syncthreads();                 // sW complete
    cg::this_grid().sync();          // slot clears visible grid-wide
    if (tid >= 64) return;           // waves 1-3 done; wave 0 runs the scan

    // ---- lane roles (wave 0) ----
    const int l  = tid;
    const int q  = l & 15;           // output col within block / A-frag batch
    const int hi = l >> 4;           // k-subchunk / D batch-group
    const int col = col0 + q;

    // input-projection weights for all 3 gates (lane-local)
    float wp[3][3], bi[3], bh[3];
    #pragma unroll
    for (int g = 0; g < 3; ++g) {
        if (col < HALFN) {
            wp[g][0] = Wc[g * HALFN + col];
            wp[g][1] = Wc[1344 + g * HALFN + col];
            wp[g][2] = 0.f;
        } else {
            int ck = col - HALFN;
            wp[g][0] = Wf[g * HALFN + ck];
            wp[g][1] = Wf[1344 + g * HALFN + ck];
            wp[g][2] = Wf[2688 + g * HALFN + ck];
        }
        bi[g] = b_ih[g * HIDN + col];
        bh[g] = b_hh[g * HIDN + col];
    }
    float hp[4] = {0.f, 0.f, 0.f, 0.f};

    // ---- x prefetch registers (single set; refilled post-publish) ----
    float xc[3][4];
    int   si0[4], si1[4], si2[4];

#define PREFETCH(tt) {                                                         \
    int tn_ = (tt) < TT ? (tt) : TT - 1;                                       \
    _Pragma("unroll")                                                          \
    for (int r_ = 0; r_ < 4; ++r_) {                                           \
        size_t bt_ = (size_t)(hi * 4 + r_) * TT + tn_;                         \
        xc[0][r_] = cond[(bt_ * 3 + 0) * HIDN + col];                          \
        xc[1][r_] = cond[(bt_ * 3 + 1) * HIDN + col];                          \
        xc[2][r_] = cond[(bt_ * 3 + 2) * HIDN + col];                          \
        si0[r_] = sig[bt_ * 2 + 0];                                            \
        si1[r_] = sig[bt_ * 2 + 1];                                            \
        si2[r_] = tcrs[bt_];                                                   \
    } }

    PREFETCH(0);

    const float inv = 1.f / 127.5f;

    // ---- single-load wait on all 56 producer slots ----
#define WAITALL(t) { bool ok_;                                                 \
    for (;;) {                                                                 \
        int a_ = (l < NWG) ? __hip_atomic_load(&slots[l * 16],                 \
            __ATOMIC_RELAXED, __HIP_MEMORY_SCOPE_AGENT) : (t);                 \
        ok_ = (a_ >= (t));                                                     \
        if (__all(ok_)) break;                                                 \
        __builtin_amdgcn_s_sleep(1);                                           \
    }                                                                          \
    asm volatile("" ::: "memory"); }

    // Lane (q,hi): A-frag for K-step ks = chunks {8ks+2hi, 8ks+2hi+1}, batch q.
#define LOADH(s, V) _Pragma("unroll")                                          \
    for (int i_ = 0; i_ < 7; ++i_) {                                           \
        _Pragma("unroll")                                                      \
        for (int h_ = 0; h_ < 2; ++h_)                                         \
            V[2*i_ + h_] = __hip_atomic_load(                                  \
                &hb[(size_t)(8 * ((s)*7 + i_) + 2 * hi + h_) * 16 + q],        \
                __ATOMIC_RELAXED, __HIP_MEMORY_SCOPE_AGENT);                   \
    }

#define MFMAS(s, V) _Pragma("unroll")                                          \
    for (int i_ = 0; i_ < 7; ++i_) {                                           \
        ull2 tv_; tv_.x = V[2*i_]; tv_.y = V[2*i_ + 1];                        \
        short8 av_ = __builtin_bit_cast(short8, tv_);                          \
        int ko_ = ((s)*7 + i_) * 32 + hi * 8;                                  \
        short8 bR_ = *(const short8*)&sW[q * WSTR + ko_];                      \
        ch[0][i_ & 1] = __builtin_amdgcn_mfma_f32_16x16x32_bf16(               \
            av_, bR_, ch[0][i_ & 1], 0, 0, 0);                                 \
        short8 bZ_ = *(const short8*)&sW[(16 + q) * WSTR + ko_];               \
        ch[1][i_ & 1] = __builtin_amdgcn_mfma_f32_16x16x32_bf16(               \
            av_, bZ_, ch[1][i_ & 1], 0, 0, 0);                                 \
        short8 bN_ = *(const short8*)&sW[(32 + q) * WSTR + ko_];               \
        ch[2][i_ & 1] = __builtin_amdgcn_mfma_f32_16x16x32_bf16(               \
            av_, bN_, ch[2][i_ & 1], 0, 0, 0);                                 \
    }

    for (int t = 0; t < TT; ++t) {
        f32x4 ch[3][2] = {};
        if (t > 0) {
            WAITALL(t);
            const unsigned long long* hb = hx + (size_t)(t & 1) * 3584;
            unsigned long long va[14], vb[14];
            LOADH(0, va);
            LOADH(1, vb);
            MFMAS(0, va);
            LOADH(2, va);
            MFMAS(1, vb);
            LOADH(3, vb);
            MFMAS(2, va);
            MFMAS(3, vb);
        }
        f32x4 aR = ch[0][0] + ch[0][1];
        f32x4 aZ = ch[1][0] + ch[1][1];
        f32x4 aN = ch[2][0] + ch[2][1];

        // ---- gates: fully lane-local (r,z,n share the D layout) ----
        float hnv[4];
        unsigned short hbits[4];
        #pragma unroll
        for (int r = 0; r < 4; ++r) {
            float g0 = (float)si0[r] * inv - 1.f;
            float g1 = (float)si1[r] * inv - 1.f;
            float g2 = (float)si2[r] * inv - 1.f;
            float xvR = xc[0][r] + bi[0] + g0*wp[0][0] + g1*wp[0][1] + g2*wp[0][2];
            float xvZ = xc[1][r] + bi[1] + g0*wp[1][0] + g1*wp[1][1] + g2*wp[1][2];
            float xvN = xc[2][r] + bi[2] + g0*wp[2][0] + g1*wp[2][1] + g2*wp[2][2];
            float sR = 1.f / (1.f + __expf(-(xvR + aR[r] + bh[0])));
            float sZ = 1.f / (1.f + __expf(-(xvZ + aZ[r] + bh[1])));
            float a2v = xvN + sR * (aN[r] + bh[2]);
            float e = __expf(-2.f * a2v);
            float n = (1.f - e) / (1.f + e);
            float hn = (1.f - sZ) * n + sZ * hp[r];
            hp[r] = hn;
            hnv[r] = hn;
            hbits[r] = f2bf(hn);
        }
        if (t == TT - 1) {
            #pragma unroll
            for (int r = 0; r < 4; ++r)
                lasth[(size_t)(hi * 4 + r) * HIDN + col] = hnv[r];
        }

        // ---- pack 16 cols -> 4 u64 chunks per batch; store; drain; publish
        unsigned p32[4];
        unsigned long long hv64[4];
        #pragma unroll
        for (int r = 0; r < 4; ++r) {
            int o1 = __shfl_xor((int)(unsigned)hbits[r], 1);
            p32[r] = ((unsigned)hbits[r] & 0xffffu) | ((unsigned)o1 << 16);
            int o2 = __shfl_xor((int)p32[r], 2);
            hv64[r] = (unsigned long long)p32[r] |
                      ((unsigned long long)(unsigned)o2 << 32);
        }
        if (t < TT - 1 && (q & 3) == 0) {
            unsigned long long* hd = hx + (size_t)((t + 1) & 1) * 3584;
            #pragma unroll
            for (int r = 0; r < 4; ++r)
                __hip_atomic_store(&hd[(size_t)(4 * cb + (q >> 2)) * 16 + hi * 4 + r],
                                   hv64[r], __ATOMIC_RELAXED, __HIP_MEMORY_SCOPE_AGENT);
        }
        asm volatile("s_waitcnt vmcnt(0)" ::: "memory");
        if (tid == 0)
            __hip_atomic_store(&slots[wg * 16], t + 1,
                               __ATOMIC_RELAXED, __HIP_MEMORY_SCOPE_AGENT);

        // ---- post-publish: prefetch next x, then history write ----
        PREFETCH(t + 1);
        if (cb < 28 && !(q & 1)) {
            unsigned* hc32 = (unsigned*)hc_out;
            #pragma unroll
            for (int r = 0; r < 4; ++r)
                hc32[((size_t)(hi * 4 + r) * TT + t) * 224 + cb * 8 + (q >> 1)] = p32[r];
        }
    }
#undef WAITALL
#undef LOADH
#undef MFMAS
#undef PREFETCH
}

// ---------------------------------------------------------------------------
// Head GEMM (MFMA bf16, r11/r12 verbatim -- ~130 us total):
// C(M x N) = [relu](A_bf16(M x 448) @ Bw_f32(448 x N) + bias).
// ---------------------------------------------------------------------------
template<int RELU_BF16>
__global__ __launch_bounds__(256)
void head_gemm(const unsigned short* __restrict__ A,
               const float* __restrict__ Bw,
               const float* __restrict__ bias,
               unsigned short* __restrict__ Cb,
               float* __restrict__ Cf,
               int N)
{
    const int K = 448;
    __shared__ unsigned short sA[128 * 40];    // 10,240 B
    __shared__ unsigned short sBt[64 * 40];    //  5,120 B (transposed: [col][k])
    const int tid = threadIdx.x;
    const int w   = tid >> 6;
    const int l   = tid & 63;
    const int wm  = (w >> 1) * 64;
    const int wn  = (w & 1) * 32;
    const int bm  = blockIdx.x * 128;
    const int bn  = blockIdx.y * 64;

    f32x4 acc[4][2] = {};

    for (int k0 = 0; k0 < K; k0 += 32) {
        #pragma unroll
        for (int it = 0; it < 2; ++it) {
            int idx = tid + it * 256;
            int row = idx >> 2;
            int ck  = (idx & 3) * 8;
            *(float4*)&sA[row * 40 + ck] =
                *(const float4*)(A + (size_t)(bm + row) * K + k0 + ck);
        }
        #pragma unroll
        for (int it = 0; it < 2; ++it) {
            int idx = tid + it * 256;
            int kk = idx >> 4;
            int c4 = (idx & 15) * 4;
            float4 v = *(const float4*)(Bw + (size_t)(k0 + kk) * N + bn + c4);
            sBt[(c4 + 0) * 40 + kk] = f2bf(v.x);
            sBt[(c4 + 1) * 40 + kk] = f2bf(v.y);
            sBt[(c4 + 2) * 40 + kk] = f2bf(v.z);
            sBt[(c4 + 3) * 40 + kk] = f2bf(v.w);
        }
        __syncthreads();
        const int kq = (l >> 4) * 8;
        short8 bv0 = *(const short8*)&sBt[(wn + (l & 15)) * 40 + kq];
        short8 bv1 = *(const short8*)&sBt[(wn + 16 + (l & 15)) * 40 + kq];
        #pragma unroll
        for (int rb = 0; rb < 4; ++rb) {
            short8 av = *(const short8*)&sA[(wm + rb * 16 + (l & 15)) * 40 + kq];
            acc[rb][0] = __builtin_amdgcn_mfma_f32_16x16x32_bf16(av, bv0, acc[rb][0], 0, 0, 0);
            acc[rb][1] = __builtin_amdgcn_mfma_f32_16x16x32_bf16(av, bv1, acc[rb][1], 0, 0, 0);
        }
        __syncthreads();
    }

    #pragma unroll
    for (int rb = 0; rb < 4; ++rb) {
        #pragma unroll
        for (int cbk = 0; cbk < 2; ++cbk) {
            int colo = bn + wn + cbk * 16 + (l & 15);
            float bv = bias[colo];
            #pragma unroll
            for (int j = 0; j < 4; ++j) {
                int row = bm + wm + rb * 16 + (l >> 4) * 4 + j;
                float v = acc[rb][cbk][j] + bv;
                if (RELU_BF16)
                    Cb[(size_t)row * N + colo] = f2bf(fmaxf(v, 0.f));
                else
                    Cf[(size_t)row * N + colo] = v;
            }
        }
    }
}

// ---------------------------------------------------------------------------
extern "C" void kernel_launch(void* const* d_in, const int* in_sizes, int n_in,
                              void* d_out, int out_size, void* d_ws, size_t ws_size,
                              hipStream_t stream)
{
    const float* cond = (const float*)d_in[0];
    const int*   sig  = (const int*)d_in[1];
    const int*   tcrs = (const int*)d_in[2];
    const float* Wc   = (const float*)d_in[3];
    const float* Wf   = (const float*)d_in[4];
    const float* Whh  = (const float*)d_in[5];
    const float* bih  = (const float*)d_in[6];
    const float* bhh  = (const float*)d_in[7];
    const float* W1c  = (const float*)d_in[8];
    const float* b1c  = (const float*)d_in[9];
    const float* W2c  = (const float*)d_in[10];
    const float* b2c  = (const float*)d_in[11];
    const float* W1f  = (const float*)d_in[12];
    const float* b1f  = (const float*)d_in[13];
    const float* W2f  = (const float*)d_in[14];
    const float* b2f  = (const float*)d_in[15];

    char* ws = (char*)d_ws;
    int* slots               = (int*)ws;                         // 3,584 B (8K pad)
    unsigned long long* hx   = (unsigned long long*)(ws + 8192); // 57,344 B
    unsigned short* hc       = (unsigned short*)(ws + 65536);    // 29,360,128 B
    unsigned short* hid1     = (unsigned short*)(ws + 65536 + 29360128);

    float* outc  = (float*)d_out;
    float* outf  = outc + (size_t)BB * TT * NBINS;
    float* lasth = outc + 2 * (size_t)BB * TT * NBINS;

    void* args[] = {(void*)&cond, (void*)&sig, (void*)&tcrs, (void*)&Wc, (void*)&Wf,
                    (void*)&Whh, (void*)&bih, (void*)&bhh,
                    (void*)&hx, (void*)&slots, (void*)&hc, (void*)&lasth};
    hipLaunchCooperativeKernel((void*)scan_kernel, dim3(NWG), dim3(NTHR),
                               args, 0, stream);

    dim3 blk(256);
    head_gemm<1><<<dim3(256, 7), blk, 0, stream>>>(hc,   W1c, b1c, hid1, nullptr, 448);
    head_gemm<0><<<dim3(256, 4), blk, 0, stream>>>(hid1, W2c, b2c, nullptr, outc, 256);
    head_gemm<1><<<dim3(256, 7), blk, 0, stream>>>(hc,   W1f, b1f, hid1, nullptr, 448);
    head_gemm<0><<<dim3(256, 4), blk, 0, stream>>>(hid1, W2f, b2f, nullptr, outf, 256);
}